// Round 13
// baseline (424.335 us; speedup 1.0000x reference)
//
#include <hip/hip_runtime.h>
#include <hip/hip_bf16.h>
#include <math.h>

// GlobalSceneTokenizer fused pipeline, f32 in/out (confirmed R3).
// pooled[b,c] = max_{i,k} LN2(gelu(LN1(gin@w1+b1))@w2+b2)[c]; final MLPs fused
// (R8 no-fence done-counter handshake). R13 = R12 (measured 379us k_main) +
// stage-2 latency hoist: w2T ks0/1 fragments and b2/g2/be2 consts issued before
// P3's stats barriers so their L2 latency drains under the LN1/gelu epilogue.
// a1s col map: [0..63]=pf | [64..66]=relxyz | [67..90]=relemb24 | [91]=0 |
//              [92..187]=absemb96 | [188..191]=0   (w1T rows remapped to match)

#define LN_EPS 1e-5f

typedef __attribute__((ext_vector_type(8))) short bf16x8;
typedef __attribute__((ext_vector_type(4))) float f32x4;
typedef __attribute__((ext_vector_type(2))) unsigned int u32x2;
typedef __attribute__((ext_vector_type(4))) unsigned int u32x4;

#if __has_builtin(__builtin_amdgcn_rcpf)
#define FRCP(x) __builtin_amdgcn_rcpf(x)
#else
#define FRCP(x) (1.0f / (x))
#endif

__device__ __forceinline__ unsigned short f2bf(float f) {
    unsigned int x = __float_as_uint(f);
    return (unsigned short)((x + 0x7FFFu + ((x >> 16) & 1u)) >> 16);  // RNE
}
// packed f32x2 -> bf16x2 via v_cvt_pk_bf16_f32 (RNE, single inst on gfx950)
__device__ __forceinline__ unsigned int pack2(float a, float b) {
    union { __hip_bfloat162 h; unsigned int u; } cvt;
    cvt.h = __float22bfloat162_rn(make_float2(a, b));
    return cvt.u;
}
__device__ __forceinline__ unsigned int fenc(float f) {
    unsigned int u = __float_as_uint(f);
    return (u & 0x80000000u) ? ~u : (u | 0x80000000u);
}
__device__ __forceinline__ float fdec(unsigned int u) {
    return __uint_as_float((u & 0x80000000u) ? (u & 0x7FFFFFFFu) : ~u);
}
// gelu, tanh-approx in sigmoid form: gelu = x * sigma(2u), u = sqrt(2/pi)(x+0.044715x^3)
__device__ __forceinline__ float gelu_fast(float x) {
    float x2 = x * x;
    float u = x * fmaf(0.0356774081f, x2, 0.7978845608f);
    float e = exp2f(u * -2.8853900818f);   // e^{-2u}
    float r = FRCP(e + 1.0f);              // sigma(2u)
    return x * r;
}
template<int CTRL>
__device__ __forceinline__ float dppadd(float s) {
    int v = __builtin_amdgcn_update_dpp(0, __float_as_int(s), CTRL, 0xF, 0xF, true);
    return s + __int_as_float(v);
}
__device__ __forceinline__ float rowsum16(float x) {
    x = dppadd<0x128>(x);   // ror:8
    x = dppadd<0x124>(x);   // ror:4
    x = dppadd<0x122>(x);   // ror:2
    x = dppadd<0x121>(x);   // ror:1
    return x;
}

// ---------------- K_prep: w2T (k-permuted), w1T (col-91-shift), pooled+done
// k-permutation pi within each 64-block: pi(nt*16+lo) = lo*4+nt.
__global__ __launch_bounds__(256) void k_prep(
    const float* __restrict__ w1, const float* __restrict__ w2,
    unsigned short* __restrict__ w2T, unsigned short* __restrict__ w1T,
    unsigned int* __restrict__ pooled, int* __restrict__ done)
{
    int t = threadIdx.x, blk = blockIdx.x;
    if (blk < 16) {                      // w2T: [n=256][k=256 permuted]
        __shared__ unsigned short tile[64][65];
        int tr = blk >> 2, tc = blk & 3;
        #pragma unroll
        for (int rr = 0; rr < 16; ++rr) {
            int kl = rr * 4 + (t >> 6), nl = t & 63;
            tile[kl][nl] = f2bf(w2[(size_t)(tr * 64 + kl) * 256 + tc * 64 + nl]);
        }
        __syncthreads();
        #pragma unroll
        for (int rr = 0; rr < 16; ++rr) {
            int nl = rr * 4 + (t >> 6), kp = t & 63;
            int kl = (kp & 3) * 16 + (kp >> 2);      // pi^-1
            w2T[(size_t)(tc * 64 + nl) * 256 + tr * 64 + kp] = tile[kl][nl];
        }
    } else if (blk < 28) {               // w1T: [n=256][k=192], zero col 91 + tail
        __shared__ unsigned short tile[64][65];
        int idx = blk - 16;
        int tr = idx >> 2, tc = idx & 3;
        #pragma unroll
        for (int rr = 0; rr < 16; ++rr) {
            int kl = rr * 4 + (t >> 6), nl = t & 63;
            int kp = tr * 64 + kl;
            float v = 0.f;
            if (kp < 91)                       v = w1[(size_t)kp * 256 + tc * 64 + nl];
            else if (kp >= 92 && kp <= 187)    v = w1[(size_t)(kp - 1) * 256 + tc * 64 + nl];
            tile[kl][nl] = f2bf(v);
        }
        __syncthreads();
        #pragma unroll
        for (int rr = 0; rr < 16; ++rr) {
            int nl = rr * 4 + (t >> 6), kl = t & 63;
            w1T[(size_t)(tc * 64 + nl) * 192 + tr * 64 + kl] = tile[kl][nl];
        }
    } else {
        unsigned int idv = fenc(-1e19f);
        for (int q = t; q < 1024; q += 256) pooled[q] = idv;
        if (t == 0) *done = 0;
    }
}

// ---------------- K_main ---------------------------------------------------
__global__ __launch_bounds__(256, 4) void k_main(
    const float* __restrict__ xyz, const float* __restrict__ pf,
    const unsigned short* __restrict__ w1T, const unsigned short* __restrict__ w2T,
    const float* __restrict__ b1, const float* __restrict__ g1,
    const float* __restrict__ be1,
    const float* __restrict__ b2, const float* __restrict__ g2,
    const float* __restrict__ be2,
    unsigned int* __restrict__ pooled, int* __restrict__ done,
    const float* __restrict__ pw1, const float* __restrict__ pb1,
    const float* __restrict__ pg1, const float* __restrict__ pbe1,
    const float* __restrict__ pw2, const float* __restrict__ pb2,
    const float* __restrict__ pg2, const float* __restrict__ pbe2,
    float* __restrict__ out)
{
    // a1s (64 x 192+8, stride 200) unioned with h1s (64 x 256+8, stride 264)
    __shared__ __align__(16) unsigned short smem[64 * 264];   // 33792 B
    __shared__ __align__(16) unsigned int epack[2 * 48];      // abs-emb bf16x2
    __shared__ unsigned long long bmask[2][64];
    __shared__ int   idxs[64];
    __shared__ float ctr[2][3];
    __shared__ int   lastf;
    unsigned short* a1s = smem;   // stride 200
    unsigned short* h1s = smem;   // stride 264 (k-permuted within 64-blocks)

    const int N = 4096;
    int tid = threadIdx.x, wv = tid >> 6, lane = tid & 63;
    int lo16 = lane & 15, quad = lane >> 4;
    int b = blockIdx.x & 3;                    // batch-major for L2 locality
    int i0 = (blockIdx.x >> 2) * 2;
    size_t base = (size_t)b * N;
    const float* xb = xyz + base * 3;

    // hoisted: first two K-steps of stage-1 weights (independent of LDS)
    bf16x8 bfr0[4], bfr1[4];
    #pragma unroll
    for (int nt = 0; nt < 4; ++nt) {
        int n = wv * 64 + nt * 16 + lo16;
        bfr0[nt] = *(const bf16x8*)&w1T[n * 192 + 0 * 32 + quad * 8];
        bfr1[nt] = *(const bf16x8*)&w1T[n * 192 + 1 * 32 + quad * 8];
    }

    // P0a: centers
    if (tid < 6) { int p = tid / 3, a = tid - 3 * p; ctr[p][a] = xb[(i0 + p) * 3 + a]; }
    // P0b: abs sin-emb packed pairs; 96 threads x 2 values; freq=10000^(-jf/15)
    if (tid < 96) {
        int p = tid / 48, pr = tid - 48 * p;       // pair 0..47 (cols 2pr,2pr+1)
        float vals[2];
        #pragma unroll
        for (int q = 0; q < 2; ++q) {
            int cc = pr * 2 + q;
            int a = cc >> 5, wI = cc & 31;
            int jf = (wI < 16) ? wI : (wI - 16);
            float coord = xb[(i0 + p) * 3 + a];
            float fr = __expf(-0.61402269146507894f * (float)jf);
            float ang = coord * fr;
            vals[q] = (wI < 16) ? __sinf(ang) : __cosf(ang);
        }
        epack[p * 48 + pr] = pack2(vals[0], vals[1]);
    }
    // exact fp32 threshold: largest float <= (double)0.16*0.16  (validated R9)
    const double r2d = 0.16 * 0.16;
    float T = (float)r2d;
    if ((double)T > r2d) T = __uint_as_float(__float_as_uint(T) - 1u);
    // P0c phase A: each wave scans 16 chunks, both centers per load
    {
        float cx0 = xb[i0 * 3], cy0 = xb[i0 * 3 + 1], cz0 = xb[i0 * 3 + 2];
        float cx1 = xb[(i0 + 1) * 3], cy1 = xb[(i0 + 1) * 3 + 1], cz1 = xb[(i0 + 1) * 3 + 2];
        #pragma unroll 4
        for (int i = 0; i < 16; ++i) {
            int chunk = wv * 16 + i;
            int j = chunk * 64 + lane;
            float px = xb[j * 3], py = xb[j * 3 + 1], pz = xb[j * 3 + 2];
            float dx0 = __fsub_rn(px, cx0), dy0 = __fsub_rn(py, cy0), dz0 = __fsub_rn(pz, cz0);
            float sq0 = __fadd_rn(__fadd_rn(__fmul_rn(dx0, dx0), __fmul_rn(dy0, dy0)),
                                  __fmul_rn(dz0, dz0));
            unsigned long long m0 = __ballot(sq0 <= T);
            float dx1 = __fsub_rn(px, cx1), dy1 = __fsub_rn(py, cy1), dz1 = __fsub_rn(pz, cz1);
            float sq1 = __fadd_rn(__fadd_rn(__fmul_rn(dx1, dx1), __fmul_rn(dy1, dy1)),
                                  __fmul_rn(dz1, dz1));
            unsigned long long m1 = __ballot(sq1 <= T);
            if (lane == 0) { bmask[0][chunk] = m0; bmask[1][chunk] = m1; }
        }
    }
    __syncthreads();
    // P0c phase B: waves 0/1 select first 32 by ascending index
    if (wv < 2) {
        int p = wv;
        unsigned long long m = bmask[p][lane];
        int c = __popcll(m);
        int inc = c;
        #pragma unroll
        for (int d = 1; d <= 32; d <<= 1) {
            int v = __shfl_up(inc, d);
            if (lane >= d) inc += v;
        }
        int exc = inc - c;
        int total = __shfl(inc, 63);
        unsigned long long lm = __ballot(m != 0ull);
        int fl = __ffsll(lm) - 1;                       // total>=1 (center in ball)
        unsigned long long mf = (unsigned long long)__shfl((long long)m, fl);
        int firstj = fl * 64 + __ffsll(mf) - 1;
        unsigned long long mm = m;
        int t = 0;
        while (mm != 0ull && (exc + t) < 32) {
            int bpos = __ffsll(mm) - 1;
            idxs[p * 32 + exc + t] = lane * 64 + bpos;
            mm &= mm - 1; ++t;
        }
        if (lane >= total && lane < 32) idxs[p * 32 + lane] = firstj;  // pad
    }
    __syncthreads();

    // P1a: gather pf -> cols 0..63, packed b128 LDS writes
    {
        int r = tid >> 2, seg = tid & 3;
        int j = idxs[r];
        const f32x4* src = (const f32x4*)(pf + (base + (size_t)j) * 64 + seg * 16);
        f32x4 v0 = src[0], v1 = src[1], v2 = src[2], v3 = src[3];
        u32x4 o0, o1;
        o0.x = pack2(v0.x, v0.y); o0.y = pack2(v0.z, v0.w);
        o0.z = pack2(v1.x, v1.y); o0.w = pack2(v1.z, v1.w);
        o1.x = pack2(v2.x, v2.y); o1.y = pack2(v2.z, v2.w);
        o1.z = pack2(v3.x, v3.y); o1.w = pack2(v3.z, v3.w);
        u32x4* dst = (u32x4*)&a1s[r * 200 + seg * 16];
        dst[0] = o0; dst[1] = o1;
    }
    // P1b: rel xyz (64..66) + rel emb (67..90) + zeros (91, 188..191)
    {
        int r = tid & 63, part = tid >> 6;
        int p = r >> 5;
        int j = idxs[r];
        float rx = xb[j * 3]     - ctr[p][0];
        float ry = xb[j * 3 + 1] - ctr[p][1];
        float rz = xb[j * 3 + 2] - ctr[p][2];
        unsigned short* arow = &a1s[r * 200];
        if (part == 0) {
            *(unsigned int*)&arow[64] = pack2(rx, ry);
            arow[66] = f2bf(rz);
            arow[91] = 0;
            *(u32x2*)&arow[188] = (u32x2){0u, 0u};
        } else {
            int a = part - 1;
            float cv = (a == 0) ? rx : ((a == 1) ? ry : rz);
            const float fr4[4] = {1.f, 0.046415888336127774f,
                                  0.0021544346900318843f, 1e-4f};  // 10000^(-j/3)
            float sn[4], cs[4];
            #pragma unroll
            for (int tt = 0; tt < 4; ++tt) {
                float ang = cv * fr4[tt];
                sn[tt] = __sinf(ang); cs[tt] = __cosf(ang);
            }
            arow[67 + a * 8 + 0] = f2bf(sn[0]); arow[67 + a * 8 + 1] = f2bf(sn[1]);
            arow[67 + a * 8 + 2] = f2bf(sn[2]); arow[67 + a * 8 + 3] = f2bf(sn[3]);
            arow[67 + a * 8 + 4] = f2bf(cs[0]); arow[67 + a * 8 + 5] = f2bf(cs[1]);
            arow[67 + a * 8 + 6] = f2bf(cs[2]); arow[67 + a * 8 + 7] = f2bf(cs[3]);
        }
    }
    // P1c: abs emb cols 92..187 — pure b64 copies of pre-packed pairs
    {
        int r = tid >> 2, part = tid & 3, p = r >> 5;
        const u32x2* e = (const u32x2*)(epack + p * 48 + part * 12);
        u32x2* dst = (u32x2*)&a1s[r * 200 + 92 + part * 24];
        #pragma unroll
        for (int q = 0; q < 6; ++q) dst[q] = e[q];
    }
    __syncthreads();

    // P2: C-init = b1; stage-1 MFMA K=192 (ks 0/1 use hoisted weights)
    f32x4 acc[4][4];
    {
        float b1f[4];
        #pragma unroll
        for (int nt = 0; nt < 4; ++nt) b1f[nt] = b1[wv * 64 + nt * 16 + lo16];
        #pragma unroll
        for (int mt = 0; mt < 4; ++mt)
            #pragma unroll
            for (int nt = 0; nt < 4; ++nt)
                #pragma unroll
                for (int reg = 0; reg < 4; ++reg) acc[mt][nt][reg] = b1f[nt];
    }
    #pragma unroll
    for (int mt = 0; mt < 4; ++mt) {
        bf16x8 afr = *(const bf16x8*)&a1s[(mt * 16 + lo16) * 200 + 0 * 32 + quad * 8];
        #pragma unroll
        for (int nt = 0; nt < 4; ++nt)
            acc[mt][nt] = __builtin_amdgcn_mfma_f32_16x16x32_bf16(
                afr, bfr0[nt], acc[mt][nt], 0, 0, 0);
    }
    #pragma unroll
    for (int mt = 0; mt < 4; ++mt) {
        bf16x8 afr = *(const bf16x8*)&a1s[(mt * 16 + lo16) * 200 + 1 * 32 + quad * 8];
        #pragma unroll
        for (int nt = 0; nt < 4; ++nt)
            acc[mt][nt] = __builtin_amdgcn_mfma_f32_16x16x32_bf16(
                afr, bfr1[nt], acc[mt][nt], 0, 0, 0);
    }
    for (int ks = 2; ks < 6; ++ks) {
        bf16x8 bfr[4];
        #pragma unroll
        for (int nt = 0; nt < 4; ++nt) {
            int n = wv * 64 + nt * 16 + lo16;
            bfr[nt] = *(const bf16x8*)&w1T[n * 192 + ks * 32 + quad * 8];
        }
        #pragma unroll
        for (int mt = 0; mt < 4; ++mt) {
            bf16x8 afr = *(const bf16x8*)&a1s[(mt * 16 + lo16) * 200 + ks * 32 + quad * 8];
            #pragma unroll
            for (int nt = 0; nt < 4; ++nt)
                acc[mt][nt] = __builtin_amdgcn_mfma_f32_16x16x32_bf16(
                    afr, bfr[nt], acc[mt][nt], 0, 0, 0);
        }
    }

    // hoist: stage-2 ks0/1 B-fragments + per-col consts; L2 latency drains
    // under the stats barriers + LN1/gelu epilogue below.
    bf16x8 w2fr0[4], w2fr1[4];
    float b2f[4], g1f[4], be1f[4], g2f[4], be2f[4];
    #pragma unroll
    for (int nt = 0; nt < 4; ++nt) {
        int n = wv * 64 + nt * 16 + lo16;
        w2fr0[nt] = *(const bf16x8*)&w2T[n * 256 + 0 * 32 + quad * 8];
        w2fr1[nt] = *(const bf16x8*)&w2T[n * 256 + 1 * 32 + quad * 8];
        b2f[nt] = b2[n];
        g1f[nt] = g1[n]; be1f[nt] = be1[n];
        g2f[nt] = g2[n]; be2f[nt] = be2[n];
    }

    // P3: LN1 stats (DPP) -> gelu -> h1s (k-permuted packed b64 writes)
    __shared__ float reds[64][4][2];
    __shared__ float musig[64][2];
    #pragma unroll
    for (int mt = 0; mt < 4; ++mt) {
        #pragma unroll
        for (int reg = 0; reg < 4; ++reg) {
            float s1 = 0.f, s2 = 0.f;
            #pragma unroll
            for (int nt = 0; nt < 4; ++nt) { float v = acc[mt][nt][reg]; s1 += v; s2 = fmaf(v, v, s2); }
            s1 = rowsum16(s1); s2 = rowsum16(s2);
            if (lo16 == 0) { int r = mt * 16 + quad * 4 + reg; reds[r][wv][0] = s1; reds[r][wv][1] = s2; }
        }
    }
    __syncthreads();   // reds ready; all waves done reading a1s
    if (tid < 64) {
        int r = tid;
        float s1 = reds[r][0][0] + reds[r][1][0] + reds[r][2][0] + reds[r][3][0];
        float s2 = reds[r][0][1] + reds[r][1][1] + reds[r][2][1] + reds[r][3][1];
        float mu = s1 * (1.f / 256.f);
        float var = fmaxf(s2 * (1.f / 256.f) - mu * mu, 0.f);
        musig[r][0] = mu; musig[r][1] = rsqrtf(var + LN_EPS);
    }
    __syncthreads();
    {
        #pragma unroll
        for (int mt = 0; mt < 4; ++mt) {
            #pragma unroll
            for (int reg = 0; reg < 4; ++reg) {
                int r = mt * 16 + quad * 4 + reg;
                float mu = musig[r][0], rs = musig[r][1];
                float v0 = gelu_fast(fmaf((acc[mt][0][reg] - mu) * rs, g1f[0], be1f[0]));
                float v1 = gelu_fast(fmaf((acc[mt][1][reg] - mu) * rs, g1f[1], be1f[1]));
                float v2 = gelu_fast(fmaf((acc[mt][2][reg] - mu) * rs, g1f[2], be1f[2]));
                float v3 = gelu_fast(fmaf((acc[mt][3][reg] - mu) * rs, g1f[3], be1f[3]));
                u32x2 w; w.x = pack2(v0, v1); w.y = pack2(v2, v3);
                *(u32x2*)&h1s[r * 264 + wv * 64 + lo16 * 4] = w;   // pi(n)=lo16*4+nt
            }
        }
    }
    __syncthreads();   // h1s ready

    // P4: stage-2 MFMA K=256 (k-permuted; w2T matches); C-init = b2;
    // ks 0/1 use the hoisted fragments.
    #pragma unroll
    for (int mt = 0; mt < 4; ++mt)
        #pragma unroll
        for (int nt = 0; nt < 4; ++nt)
            #pragma unroll
            for (int reg = 0; reg < 4; ++reg) acc[mt][nt][reg] = b2f[nt];
    #pragma unroll
    for (int mt = 0; mt < 4; ++mt) {
        bf16x8 afr = *(const bf16x8*)&h1s[(mt * 16 + lo16) * 264 + 0 * 32 + quad * 8];
        #pragma unroll
        for (int nt = 0; nt < 4; ++nt)
            acc[mt][nt] = __builtin_amdgcn_mfma_f32_16x16x32_bf16(
                afr, w2fr0[nt], acc[mt][nt], 0, 0, 0);
    }
    #pragma unroll
    for (int mt = 0; mt < 4; ++mt) {
        bf16x8 afr = *(const bf16x8*)&h1s[(mt * 16 + lo16) * 264 + 1 * 32 + quad * 8];
        #pragma unroll
        for (int nt = 0; nt < 4; ++nt)
            acc[mt][nt] = __builtin_amdgcn_mfma_f32_16x16x32_bf16(
                afr, w2fr1[nt], acc[mt][nt], 0, 0, 0);
    }
    for (int ks = 2; ks < 8; ++ks) {
        bf16x8 bfr[4], afr[4];
        #pragma unroll
        for (int nt = 0; nt < 4; ++nt) {
            int n = wv * 64 + nt * 16 + lo16;
            bfr[nt] = *(const bf16x8*)&w2T[n * 256 + ks * 32 + quad * 8];
        }
        #pragma unroll
        for (int mt = 0; mt < 4; ++mt)
            afr[mt] = *(const bf16x8*)&h1s[(mt * 16 + lo16) * 264 + ks * 32 + quad * 8];
        #pragma unroll
        for (int mt = 0; mt < 4; ++mt)
            #pragma unroll
            for (int nt = 0; nt < 4; ++nt)
                acc[mt][nt] = __builtin_amdgcn_mfma_f32_16x16x32_bf16(
                    afr[mt], bfr[nt], acc[mt][nt], 0, 0, 0);
    }

    // P5: LN2 stats (DPP), normalize, row-max -> atomicMax
    {
        #pragma unroll
        for (int mt = 0; mt < 4; ++mt) {
            #pragma unroll
            for (int reg = 0; reg < 4; ++reg) {
                float s1 = 0.f, s2 = 0.f;
                #pragma unroll
                for (int nt = 0; nt < 4; ++nt) { float v = acc[mt][nt][reg]; s1 += v; s2 = fmaf(v, v, s2); }
                s1 = rowsum16(s1); s2 = rowsum16(s2);
                if (lo16 == 0) { int r = mt * 16 + quad * 4 + reg; reds[r][wv][0] = s1; reds[r][wv][1] = s2; }
            }
        }
        __syncthreads();
        if (tid < 64) {
            int r = tid;
            float s1 = reds[r][0][0] + reds[r][1][0] + reds[r][2][0] + reds[r][3][0];
            float s2 = reds[r][0][1] + reds[r][1][1] + reds[r][2][1] + reds[r][3][1];
            float mu = s1 * (1.f / 256.f);
            float var = fmaxf(s2 * (1.f / 256.f) - mu * mu, 0.f);
            musig[r][0] = mu; musig[r][1] = rsqrtf(var + LN_EPS);
        }
        __syncthreads();

        float mx[4] = {-1e30f, -1e30f, -1e30f, -1e30f};
        #pragma unroll
        for (int mt = 0; mt < 4; ++mt) {
            #pragma unroll
            for (int reg = 0; reg < 4; ++reg) {
                int r = mt * 16 + quad * 4 + reg;
                float mu = musig[r][0], rs = musig[r][1];
                #pragma unroll
                for (int nt = 0; nt < 4; ++nt) {
                    float v = fmaf((acc[mt][nt][reg] - mu) * rs, g2f[nt], be2f[nt]);
                    mx[nt] = fmaxf(mx[nt], v);
                }
            }
        }
        #pragma unroll
        for (int nt = 0; nt < 4; ++nt) {
            mx[nt] = fmaxf(mx[nt], __shfl_xor(mx[nt], 16));
            mx[nt] = fmaxf(mx[nt], __shfl_xor(mx[nt], 32));
        }
        if (quad == 0) {
            #pragma unroll
            for (int nt = 0; nt < 4; ++nt)
                atomicMax(pooled + b * 256 + wv * 64 + nt * 16 + lo16, fenc(mx[nt]));
        }
    }

    // P6: handshake (no fences) + last-block final MLPs (validated R8)
    __syncthreads();
    if (tid == 0) lastf = (atomicAdd(done, 1) == 8191);
    __syncthreads();
    if (!lastf) return;
    {
        int bb = wv;
        float* xw = (float*)smem + wv * 512;
        #pragma unroll
        for (int q = 0; q < 4; ++q)
            xw[q * 64 + lane] =
                fdec(atomicMax(&pooled[bb * 256 + q * 64 + lane], 0u));

        float a1[4];
        #pragma unroll
        for (int q = 0; q < 4; ++q) a1[q] = pb1[q * 64 + lane];
        #pragma unroll 4
        for (int k = 0; k < 256; ++k) {
            float xv = xw[k];
            const float* wr = pw1 + (size_t)k * 256 + lane;
            #pragma unroll
            for (int q = 0; q < 4; ++q) a1[q] = fmaf(xv, wr[q * 64], a1[q]);
        }
        float s1 = a1[0] + a1[1] + a1[2] + a1[3];
        float s2 = fmaf(a1[0], a1[0], fmaf(a1[1], a1[1],
                   fmaf(a1[2], a1[2], a1[3] * a1[3])));
        s1 = rowsum16(s1); s2 = rowsum16(s2);
        s1 += __shfl_xor(s1, 16); s2 += __shfl_xor(s2, 16);
        s1 += __shfl_xor(s1, 32); s2 += __shfl_xor(s2, 32);
        float mu = s1 * (1.f / 256.f);
        float rs = rsqrtf(fmaxf(s2 * (1.f / 256.f) - mu * mu, 0.f) + LN_EPS);
        #pragma unroll
        for (int q = 0; q < 4; ++q) {
            int c = q * 64 + lane;
            xw[256 + c] = gelu_fast(fmaf((a1[q] - mu) * rs, pg1[c], pbe1[c]));
        }

        float a2[4];
        #pragma unroll
        for (int q = 0; q < 4; ++q) a2[q] = pb2[q * 64 + lane];
        #pragma unroll 4
        for (int k = 0; k < 256; ++k) {
            float xv = xw[256 + k];
            const float* wr = pw2 + (size_t)k * 256 + lane;
            #pragma unroll
            for (int q = 0; q < 4; ++q) a2[q] = fmaf(xv, wr[q * 64], a2[q]);
        }
        s1 = a2[0] + a2[1] + a2[2] + a2[3];
        s2 = fmaf(a2[0], a2[0], fmaf(a2[1], a2[1],
             fmaf(a2[2], a2[2], a2[3] * a2[3])));
        s1 = rowsum16(s1); s2 = rowsum16(s2);
        s1 += __shfl_xor(s1, 16); s2 += __shfl_xor(s2, 16);
        s1 += __shfl_xor(s1, 32); s2 += __shfl_xor(s2, 32);
        mu = s1 * (1.f / 256.f);
        rs = rsqrtf(fmaxf(s2 * (1.f / 256.f) - mu * mu, 0.f) + LN_EPS);
        #pragma unroll
        for (int q = 0; q < 4; ++q) {
            int c = q * 64 + lane;
            out[bb * 256 + c] = fmaf((a2[q] - mu) * rs, pg2[c], pbe2[c]);
        }
    }
}

// ---------------- launch ---------------------------------------------------
extern "C" void kernel_launch(void* const* d_in, const int* in_sizes, int n_in,
                              void* d_out, int out_size, void* d_ws, size_t ws_size,
                              hipStream_t stream)
{
    char* ws = (char*)d_ws;
    unsigned short* w2T    = (unsigned short*)ws;                      // 128 KB
    unsigned short* w1T    = (unsigned short*)(ws + (128u << 10));     // 96 KB
    unsigned int*   pooled = (unsigned int*)(ws + (224u << 10));       // 4 KB
    int*            done   = (int*)(ws + (228u << 10));                // 4 B

    k_prep<<<29, 256, 0, stream>>>((const float*)d_in[2], (const float*)d_in[6],
                                   w2T, w1T, pooled, done);
    k_main<<<8192, 256, 0, stream>>>((const float*)d_in[0], (const float*)d_in[1],
                                     w1T, w2T,
                                     (const float*)d_in[3], (const float*)d_in[4],
                                     (const float*)d_in[5],
                                     (const float*)d_in[7], (const float*)d_in[8],
                                     (const float*)d_in[9], pooled, done,
                                     (const float*)d_in[10], (const float*)d_in[11],
                                     (const float*)d_in[12], (const float*)d_in[13],
                                     (const float*)d_in[14], (const float*)d_in[15],
                                     (const float*)d_in[16], (const float*)d_in[17],
                                     (float*)d_out);
}

// Round 14
// 414.537 us; speedup vs baseline: 1.0236x; 1.0236x over previous
//
#include <hip/hip_runtime.h>
#include <hip/hip_bf16.h>
#include <math.h>

// GlobalSceneTokenizer fused pipeline, f32 in/out (confirmed R3).
// pooled[b,c] = max_{i,k} LN2(gelu(LN1(gin@w1+b1))@w2+b2)[c]; final MLPs fused
// (R8 no-fence done-counter handshake). R14 = exact revert to R12 (measured best,
// 415.7us total / 379us k_main). R13's stage-2 hoist spilled to scratch (WRITE
// 11.5->67MB at the 64-VGPR ceiling) — register file is exactly saturated at
// this occupancy; structural search exhausted (R9 row-ownership spilled, R11
// half-tile doubled fixed costs, R13 hoist spilled).
// a1s col map: [0..63]=pf | [64..66]=relxyz | [67..90]=relemb24 | [91]=0 |
//              [92..187]=absemb96 | [188..191]=0   (w1T rows remapped to match)

#define LN_EPS 1e-5f

typedef __attribute__((ext_vector_type(8))) short bf16x8;
typedef __attribute__((ext_vector_type(4))) float f32x4;
typedef __attribute__((ext_vector_type(2))) unsigned int u32x2;
typedef __attribute__((ext_vector_type(4))) unsigned int u32x4;

#if __has_builtin(__builtin_amdgcn_rcpf)
#define FRCP(x) __builtin_amdgcn_rcpf(x)
#else
#define FRCP(x) (1.0f / (x))
#endif

__device__ __forceinline__ unsigned short f2bf(float f) {
    unsigned int x = __float_as_uint(f);
    return (unsigned short)((x + 0x7FFFu + ((x >> 16) & 1u)) >> 16);  // RNE
}
// packed f32x2 -> bf16x2 via v_cvt_pk_bf16_f32 (RNE, single inst on gfx950)
__device__ __forceinline__ unsigned int pack2(float a, float b) {
    union { __hip_bfloat162 h; unsigned int u; } cvt;
    cvt.h = __float22bfloat162_rn(make_float2(a, b));
    return cvt.u;
}
__device__ __forceinline__ unsigned int fenc(float f) {
    unsigned int u = __float_as_uint(f);
    return (u & 0x80000000u) ? ~u : (u | 0x80000000u);
}
__device__ __forceinline__ float fdec(unsigned int u) {
    return __uint_as_float((u & 0x80000000u) ? (u & 0x7FFFFFFFu) : ~u);
}
// gelu, tanh-approx in sigmoid form: gelu = x * sigma(2u), u = sqrt(2/pi)(x+0.044715x^3)
__device__ __forceinline__ float gelu_fast(float x) {
    float x2 = x * x;
    float u = x * fmaf(0.0356774081f, x2, 0.7978845608f);
    float e = exp2f(u * -2.8853900818f);   // e^{-2u}
    float r = FRCP(e + 1.0f);              // sigma(2u)
    return x * r;
}
template<int CTRL>
__device__ __forceinline__ float dppadd(float s) {
    int v = __builtin_amdgcn_update_dpp(0, __float_as_int(s), CTRL, 0xF, 0xF, true);
    return s + __int_as_float(v);
}
__device__ __forceinline__ float rowsum16(float x) {
    x = dppadd<0x128>(x);   // ror:8
    x = dppadd<0x124>(x);   // ror:4
    x = dppadd<0x122>(x);   // ror:2
    x = dppadd<0x121>(x);   // ror:1
    return x;
}

// ---------------- K_prep: w2T (k-permuted), w1T (col-91-shift), pooled+done
// k-permutation pi within each 64-block: pi(nt*16+lo) = lo*4+nt.
__global__ __launch_bounds__(256) void k_prep(
    const float* __restrict__ w1, const float* __restrict__ w2,
    unsigned short* __restrict__ w2T, unsigned short* __restrict__ w1T,
    unsigned int* __restrict__ pooled, int* __restrict__ done)
{
    int t = threadIdx.x, blk = blockIdx.x;
    if (blk < 16) {                      // w2T: [n=256][k=256 permuted]
        __shared__ unsigned short tile[64][65];
        int tr = blk >> 2, tc = blk & 3;
        #pragma unroll
        for (int rr = 0; rr < 16; ++rr) {
            int kl = rr * 4 + (t >> 6), nl = t & 63;
            tile[kl][nl] = f2bf(w2[(size_t)(tr * 64 + kl) * 256 + tc * 64 + nl]);
        }
        __syncthreads();
        #pragma unroll
        for (int rr = 0; rr < 16; ++rr) {
            int nl = rr * 4 + (t >> 6), kp = t & 63;
            int kl = (kp & 3) * 16 + (kp >> 2);      // pi^-1
            w2T[(size_t)(tc * 64 + nl) * 256 + tr * 64 + kp] = tile[kl][nl];
        }
    } else if (blk < 28) {               // w1T: [n=256][k=192], zero col 91 + tail
        __shared__ unsigned short tile[64][65];
        int idx = blk - 16;
        int tr = idx >> 2, tc = idx & 3;
        #pragma unroll
        for (int rr = 0; rr < 16; ++rr) {
            int kl = rr * 4 + (t >> 6), nl = t & 63;
            int kp = tr * 64 + kl;
            float v = 0.f;
            if (kp < 91)                       v = w1[(size_t)kp * 256 + tc * 64 + nl];
            else if (kp >= 92 && kp <= 187)    v = w1[(size_t)(kp - 1) * 256 + tc * 64 + nl];
            tile[kl][nl] = f2bf(v);
        }
        __syncthreads();
        #pragma unroll
        for (int rr = 0; rr < 16; ++rr) {
            int nl = rr * 4 + (t >> 6), kl = t & 63;
            w1T[(size_t)(tc * 64 + nl) * 192 + tr * 64 + kl] = tile[kl][nl];
        }
    } else {
        unsigned int idv = fenc(-1e19f);
        for (int q = t; q < 1024; q += 256) pooled[q] = idv;
        if (t == 0) *done = 0;
    }
}

// ---------------- K_main ---------------------------------------------------
__global__ __launch_bounds__(256, 4) void k_main(
    const float* __restrict__ xyz, const float* __restrict__ pf,
    const unsigned short* __restrict__ w1T, const unsigned short* __restrict__ w2T,
    const float* __restrict__ b1, const float* __restrict__ g1,
    const float* __restrict__ be1,
    const float* __restrict__ b2, const float* __restrict__ g2,
    const float* __restrict__ be2,
    unsigned int* __restrict__ pooled, int* __restrict__ done,
    const float* __restrict__ pw1, const float* __restrict__ pb1,
    const float* __restrict__ pg1, const float* __restrict__ pbe1,
    const float* __restrict__ pw2, const float* __restrict__ pb2,
    const float* __restrict__ pg2, const float* __restrict__ pbe2,
    float* __restrict__ out)
{
    // a1s (64 x 192+8, stride 200) unioned with h1s (64 x 256+8, stride 264)
    __shared__ __align__(16) unsigned short smem[64 * 264];   // 33792 B
    __shared__ __align__(16) unsigned int epack[2 * 48];      // abs-emb bf16x2
    __shared__ unsigned long long bmask[2][64];
    __shared__ int   idxs[64];
    __shared__ float ctr[2][3];
    __shared__ int   lastf;
    unsigned short* a1s = smem;   // stride 200
    unsigned short* h1s = smem;   // stride 264 (k-permuted within 64-blocks)

    const int N = 4096;
    int tid = threadIdx.x, wv = tid >> 6, lane = tid & 63;
    int lo16 = lane & 15, quad = lane >> 4;
    int b = blockIdx.x & 3;                    // batch-major for L2 locality
    int i0 = (blockIdx.x >> 2) * 2;
    size_t base = (size_t)b * N;
    const float* xb = xyz + base * 3;

    // hoisted: first two K-steps of stage-1 weights (independent of LDS)
    bf16x8 bfr0[4], bfr1[4];
    #pragma unroll
    for (int nt = 0; nt < 4; ++nt) {
        int n = wv * 64 + nt * 16 + lo16;
        bfr0[nt] = *(const bf16x8*)&w1T[n * 192 + 0 * 32 + quad * 8];
        bfr1[nt] = *(const bf16x8*)&w1T[n * 192 + 1 * 32 + quad * 8];
    }

    // P0a: centers
    if (tid < 6) { int p = tid / 3, a = tid - 3 * p; ctr[p][a] = xb[(i0 + p) * 3 + a]; }
    // P0b: abs sin-emb packed pairs; 96 threads x 2 values; freq=10000^(-jf/15)
    if (tid < 96) {
        int p = tid / 48, pr = tid - 48 * p;       // pair 0..47 (cols 2pr,2pr+1)
        float vals[2];
        #pragma unroll
        for (int q = 0; q < 2; ++q) {
            int cc = pr * 2 + q;
            int a = cc >> 5, wI = cc & 31;
            int jf = (wI < 16) ? wI : (wI - 16);
            float coord = xb[(i0 + p) * 3 + a];
            float fr = __expf(-0.61402269146507894f * (float)jf);
            float ang = coord * fr;
            vals[q] = (wI < 16) ? __sinf(ang) : __cosf(ang);
        }
        epack[p * 48 + pr] = pack2(vals[0], vals[1]);
    }
    // exact fp32 threshold: largest float <= (double)0.16*0.16  (validated R9)
    const double r2d = 0.16 * 0.16;
    float T = (float)r2d;
    if ((double)T > r2d) T = __uint_as_float(__float_as_uint(T) - 1u);
    // P0c phase A: each wave scans 16 chunks, both centers per load
    {
        float cx0 = xb[i0 * 3], cy0 = xb[i0 * 3 + 1], cz0 = xb[i0 * 3 + 2];
        float cx1 = xb[(i0 + 1) * 3], cy1 = xb[(i0 + 1) * 3 + 1], cz1 = xb[(i0 + 1) * 3 + 2];
        #pragma unroll 4
        for (int i = 0; i < 16; ++i) {
            int chunk = wv * 16 + i;
            int j = chunk * 64 + lane;
            float px = xb[j * 3], py = xb[j * 3 + 1], pz = xb[j * 3 + 2];
            float dx0 = __fsub_rn(px, cx0), dy0 = __fsub_rn(py, cy0), dz0 = __fsub_rn(pz, cz0);
            float sq0 = __fadd_rn(__fadd_rn(__fmul_rn(dx0, dx0), __fmul_rn(dy0, dy0)),
                                  __fmul_rn(dz0, dz0));
            unsigned long long m0 = __ballot(sq0 <= T);
            float dx1 = __fsub_rn(px, cx1), dy1 = __fsub_rn(py, cy1), dz1 = __fsub_rn(pz, cz1);
            float sq1 = __fadd_rn(__fadd_rn(__fmul_rn(dx1, dx1), __fmul_rn(dy1, dy1)),
                                  __fmul_rn(dz1, dz1));
            unsigned long long m1 = __ballot(sq1 <= T);
            if (lane == 0) { bmask[0][chunk] = m0; bmask[1][chunk] = m1; }
        }
    }
    __syncthreads();
    // P0c phase B: waves 0/1 select first 32 by ascending index
    if (wv < 2) {
        int p = wv;
        unsigned long long m = bmask[p][lane];
        int c = __popcll(m);
        int inc = c;
        #pragma unroll
        for (int d = 1; d <= 32; d <<= 1) {
            int v = __shfl_up(inc, d);
            if (lane >= d) inc += v;
        }
        int exc = inc - c;
        int total = __shfl(inc, 63);
        unsigned long long lm = __ballot(m != 0ull);
        int fl = __ffsll(lm) - 1;                       // total>=1 (center in ball)
        unsigned long long mf = (unsigned long long)__shfl((long long)m, fl);
        int firstj = fl * 64 + __ffsll(mf) - 1;
        unsigned long long mm = m;
        int t = 0;
        while (mm != 0ull && (exc + t) < 32) {
            int bpos = __ffsll(mm) - 1;
            idxs[p * 32 + exc + t] = lane * 64 + bpos;
            mm &= mm - 1; ++t;
        }
        if (lane >= total && lane < 32) idxs[p * 32 + lane] = firstj;  // pad
    }
    __syncthreads();

    // P1a: gather pf -> cols 0..63, packed b128 LDS writes
    {
        int r = tid >> 2, seg = tid & 3;
        int j = idxs[r];
        const f32x4* src = (const f32x4*)(pf + (base + (size_t)j) * 64 + seg * 16);
        f32x4 v0 = src[0], v1 = src[1], v2 = src[2], v3 = src[3];
        u32x4 o0, o1;
        o0.x = pack2(v0.x, v0.y); o0.y = pack2(v0.z, v0.w);
        o0.z = pack2(v1.x, v1.y); o0.w = pack2(v1.z, v1.w);
        o1.x = pack2(v2.x, v2.y); o1.y = pack2(v2.z, v2.w);
        o1.z = pack2(v3.x, v3.y); o1.w = pack2(v3.z, v3.w);
        u32x4* dst = (u32x4*)&a1s[r * 200 + seg * 16];
        dst[0] = o0; dst[1] = o1;
    }
    // P1b: rel xyz (64..66) + rel emb (67..90) + zeros (91, 188..191)
    {
        int r = tid & 63, part = tid >> 6;
        int p = r >> 5;
        int j = idxs[r];
        float rx = xb[j * 3]     - ctr[p][0];
        float ry = xb[j * 3 + 1] - ctr[p][1];
        float rz = xb[j * 3 + 2] - ctr[p][2];
        unsigned short* arow = &a1s[r * 200];
        if (part == 0) {
            *(unsigned int*)&arow[64] = pack2(rx, ry);
            arow[66] = f2bf(rz);
            arow[91] = 0;
            *(u32x2*)&arow[188] = (u32x2){0u, 0u};
        } else {
            int a = part - 1;
            float cv = (a == 0) ? rx : ((a == 1) ? ry : rz);
            const float fr4[4] = {1.f, 0.046415888336127774f,
                                  0.0021544346900318843f, 1e-4f};  // 10000^(-j/3)
            float sn[4], cs[4];
            #pragma unroll
            for (int tt = 0; tt < 4; ++tt) {
                float ang = cv * fr4[tt];
                sn[tt] = __sinf(ang); cs[tt] = __cosf(ang);
            }
            arow[67 + a * 8 + 0] = f2bf(sn[0]); arow[67 + a * 8 + 1] = f2bf(sn[1]);
            arow[67 + a * 8 + 2] = f2bf(sn[2]); arow[67 + a * 8 + 3] = f2bf(sn[3]);
            arow[67 + a * 8 + 4] = f2bf(cs[0]); arow[67 + a * 8 + 5] = f2bf(cs[1]);
            arow[67 + a * 8 + 6] = f2bf(cs[2]); arow[67 + a * 8 + 7] = f2bf(cs[3]);
        }
    }
    // P1c: abs emb cols 92..187 — pure b64 copies of pre-packed pairs
    {
        int r = tid >> 2, part = tid & 3, p = r >> 5;
        const u32x2* e = (const u32x2*)(epack + p * 48 + part * 12);
        u32x2* dst = (u32x2*)&a1s[r * 200 + 92 + part * 24];
        #pragma unroll
        for (int q = 0; q < 6; ++q) dst[q] = e[q];
    }
    __syncthreads();

    // P2: C-init = b1; stage-1 MFMA K=192 (ks 0/1 use hoisted weights)
    f32x4 acc[4][4];
    {
        float b1f[4];
        #pragma unroll
        for (int nt = 0; nt < 4; ++nt) b1f[nt] = b1[wv * 64 + nt * 16 + lo16];
        #pragma unroll
        for (int mt = 0; mt < 4; ++mt)
            #pragma unroll
            for (int nt = 0; nt < 4; ++nt)
                #pragma unroll
                for (int reg = 0; reg < 4; ++reg) acc[mt][nt][reg] = b1f[nt];
    }
    #pragma unroll
    for (int mt = 0; mt < 4; ++mt) {
        bf16x8 afr = *(const bf16x8*)&a1s[(mt * 16 + lo16) * 200 + 0 * 32 + quad * 8];
        #pragma unroll
        for (int nt = 0; nt < 4; ++nt)
            acc[mt][nt] = __builtin_amdgcn_mfma_f32_16x16x32_bf16(
                afr, bfr0[nt], acc[mt][nt], 0, 0, 0);
    }
    #pragma unroll
    for (int mt = 0; mt < 4; ++mt) {
        bf16x8 afr = *(const bf16x8*)&a1s[(mt * 16 + lo16) * 200 + 1 * 32 + quad * 8];
        #pragma unroll
        for (int nt = 0; nt < 4; ++nt)
            acc[mt][nt] = __builtin_amdgcn_mfma_f32_16x16x32_bf16(
                afr, bfr1[nt], acc[mt][nt], 0, 0, 0);
    }
    for (int ks = 2; ks < 6; ++ks) {
        bf16x8 bfr[4];
        #pragma unroll
        for (int nt = 0; nt < 4; ++nt) {
            int n = wv * 64 + nt * 16 + lo16;
            bfr[nt] = *(const bf16x8*)&w1T[n * 192 + ks * 32 + quad * 8];
        }
        #pragma unroll
        for (int mt = 0; mt < 4; ++mt) {
            bf16x8 afr = *(const bf16x8*)&a1s[(mt * 16 + lo16) * 200 + ks * 32 + quad * 8];
            #pragma unroll
            for (int nt = 0; nt < 4; ++nt)
                acc[mt][nt] = __builtin_amdgcn_mfma_f32_16x16x32_bf16(
                    afr, bfr[nt], acc[mt][nt], 0, 0, 0);
        }
    }

    // P3: LN1 stats (DPP) -> gelu -> h1s (k-permuted packed b64 writes)
    __shared__ float reds[64][4][2];
    __shared__ float musig[64][2];
    #pragma unroll
    for (int mt = 0; mt < 4; ++mt) {
        #pragma unroll
        for (int reg = 0; reg < 4; ++reg) {
            float s1 = 0.f, s2 = 0.f;
            #pragma unroll
            for (int nt = 0; nt < 4; ++nt) { float v = acc[mt][nt][reg]; s1 += v; s2 = fmaf(v, v, s2); }
            s1 = rowsum16(s1); s2 = rowsum16(s2);
            if (lo16 == 0) { int r = mt * 16 + quad * 4 + reg; reds[r][wv][0] = s1; reds[r][wv][1] = s2; }
        }
    }
    __syncthreads();   // reds ready; all waves done reading a1s
    if (tid < 64) {
        int r = tid;
        float s1 = reds[r][0][0] + reds[r][1][0] + reds[r][2][0] + reds[r][3][0];
        float s2 = reds[r][0][1] + reds[r][1][1] + reds[r][2][1] + reds[r][3][1];
        float mu = s1 * (1.f / 256.f);
        float var = fmaxf(s2 * (1.f / 256.f) - mu * mu, 0.f);
        musig[r][0] = mu; musig[r][1] = rsqrtf(var + LN_EPS);
    }
    __syncthreads();
    {
        float g1f[4], be1f[4];
        #pragma unroll
        for (int nt = 0; nt < 4; ++nt) {
            int n = wv * 64 + nt * 16 + lo16;
            g1f[nt] = g1[n]; be1f[nt] = be1[n];
        }
        #pragma unroll
        for (int mt = 0; mt < 4; ++mt) {
            #pragma unroll
            for (int reg = 0; reg < 4; ++reg) {
                int r = mt * 16 + quad * 4 + reg;
                float mu = musig[r][0], rs = musig[r][1];
                float v0 = gelu_fast(fmaf((acc[mt][0][reg] - mu) * rs, g1f[0], be1f[0]));
                float v1 = gelu_fast(fmaf((acc[mt][1][reg] - mu) * rs, g1f[1], be1f[1]));
                float v2 = gelu_fast(fmaf((acc[mt][2][reg] - mu) * rs, g1f[2], be1f[2]));
                float v3 = gelu_fast(fmaf((acc[mt][3][reg] - mu) * rs, g1f[3], be1f[3]));
                u32x2 w; w.x = pack2(v0, v1); w.y = pack2(v2, v3);
                *(u32x2*)&h1s[r * 264 + wv * 64 + lo16 * 4] = w;   // pi(n)=lo16*4+nt
            }
        }
    }
    __syncthreads();   // h1s ready

    // P4: stage-2 MFMA K=256 (k-permuted; w2T permuted to match); C-init = b2
    {
        float b2f[4];
        #pragma unroll
        for (int nt = 0; nt < 4; ++nt) b2f[nt] = b2[wv * 64 + nt * 16 + lo16];
        #pragma unroll
        for (int mt = 0; mt < 4; ++mt)
            #pragma unroll
            for (int nt = 0; nt < 4; ++nt)
                #pragma unroll
                for (int reg = 0; reg < 4; ++reg) acc[mt][nt][reg] = b2f[nt];
    }
    for (int ks = 0; ks < 8; ++ks) {
        bf16x8 bfr[4], afr[4];
        #pragma unroll
        for (int nt = 0; nt < 4; ++nt) {
            int n = wv * 64 + nt * 16 + lo16;
            bfr[nt] = *(const bf16x8*)&w2T[n * 256 + ks * 32 + quad * 8];
        }
        #pragma unroll
        for (int mt = 0; mt < 4; ++mt)
            afr[mt] = *(const bf16x8*)&h1s[(mt * 16 + lo16) * 264 + ks * 32 + quad * 8];
        #pragma unroll
        for (int mt = 0; mt < 4; ++mt)
            #pragma unroll
            for (int nt = 0; nt < 4; ++nt)
                acc[mt][nt] = __builtin_amdgcn_mfma_f32_16x16x32_bf16(
                    afr[mt], bfr[nt], acc[mt][nt], 0, 0, 0);
    }

    // P5: LN2 stats (DPP), normalize, row-max -> atomicMax
    {
        #pragma unroll
        for (int mt = 0; mt < 4; ++mt) {
            #pragma unroll
            for (int reg = 0; reg < 4; ++reg) {
                float s1 = 0.f, s2 = 0.f;
                #pragma unroll
                for (int nt = 0; nt < 4; ++nt) { float v = acc[mt][nt][reg]; s1 += v; s2 = fmaf(v, v, s2); }
                s1 = rowsum16(s1); s2 = rowsum16(s2);
                if (lo16 == 0) { int r = mt * 16 + quad * 4 + reg; reds[r][wv][0] = s1; reds[r][wv][1] = s2; }
            }
        }
        __syncthreads();
        if (tid < 64) {
            int r = tid;
            float s1 = reds[r][0][0] + reds[r][1][0] + reds[r][2][0] + reds[r][3][0];
            float s2 = reds[r][0][1] + reds[r][1][1] + reds[r][2][1] + reds[r][3][1];
            float mu = s1 * (1.f / 256.f);
            float var = fmaxf(s2 * (1.f / 256.f) - mu * mu, 0.f);
            musig[r][0] = mu; musig[r][1] = rsqrtf(var + LN_EPS);
        }
        __syncthreads();

        float g2f[4], be2f[4];
        #pragma unroll
        for (int nt = 0; nt < 4; ++nt) {
            int n = wv * 64 + nt * 16 + lo16;
            g2f[nt] = g2[n]; be2f[nt] = be2[n];
        }
        float mx[4] = {-1e30f, -1e30f, -1e30f, -1e30f};
        #pragma unroll
        for (int mt = 0; mt < 4; ++mt) {
            #pragma unroll
            for (int reg = 0; reg < 4; ++reg) {
                int r = mt * 16 + quad * 4 + reg;
                float mu = musig[r][0], rs = musig[r][1];
                #pragma unroll
                for (int nt = 0; nt < 4; ++nt) {
                    float v = fmaf((acc[mt][nt][reg] - mu) * rs, g2f[nt], be2f[nt]);
                    mx[nt] = fmaxf(mx[nt], v);
                }
            }
        }
        #pragma unroll
        for (int nt = 0; nt < 4; ++nt) {
            mx[nt] = fmaxf(mx[nt], __shfl_xor(mx[nt], 16));
            mx[nt] = fmaxf(mx[nt], __shfl_xor(mx[nt], 32));
        }
        if (quad == 0) {
            #pragma unroll
            for (int nt = 0; nt < 4; ++nt)
                atomicMax(pooled + b * 256 + wv * 64 + nt * 16 + lo16, fenc(mx[nt]));
        }
    }

    // P6: handshake (no fences) + last-block final MLPs (validated R8)
    __syncthreads();
    if (tid == 0) lastf = (atomicAdd(done, 1) == 8191);
    __syncthreads();
    if (!lastf) return;
    {
        int bb = wv;
        float* xw = (float*)smem + wv * 512;
        #pragma unroll
        for (int q = 0; q < 4; ++q)
            xw[q * 64 + lane] =
                fdec(atomicMax(&pooled[bb * 256 + q * 64 + lane], 0u));

        float a1[4];
        #pragma unroll
        for (int q = 0; q < 4; ++q) a1[q] = pb1[q * 64 + lane];
        #pragma unroll 4
        for (int k = 0; k < 256; ++k) {
            float xv = xw[k];
            const float* wr = pw1 + (size_t)k * 256 + lane;
            #pragma unroll
            for (int q = 0; q < 4; ++q) a1[q] = fmaf(xv, wr[q * 64], a1[q]);
        }
        float s1 = a1[0] + a1[1] + a1[2] + a1[3];
        float s2 = fmaf(a1[0], a1[0], fmaf(a1[1], a1[1],
                   fmaf(a1[2], a1[2], a1[3] * a1[3])));
        s1 = rowsum16(s1); s2 = rowsum16(s2);
        s1 += __shfl_xor(s1, 16); s2 += __shfl_xor(s2, 16);
        s1 += __shfl_xor(s1, 32); s2 += __shfl_xor(s2, 32);
        float mu = s1 * (1.f / 256.f);
        float rs = rsqrtf(fmaxf(s2 * (1.f / 256.f) - mu * mu, 0.f) + LN_EPS);
        #pragma unroll
        for (int q = 0; q < 4; ++q) {
            int c = q * 64 + lane;
            xw[256 + c] = gelu_fast(fmaf((a1[q] - mu) * rs, pg1[c], pbe1[c]));
        }

        float a2[4];
        #pragma unroll
        for (int q = 0; q < 4; ++q) a2[q] = pb2[q * 64 + lane];
        #pragma unroll 4
        for (int k = 0; k < 256; ++k) {
            float xv = xw[256 + k];
            const float* wr = pw2 + (size_t)k * 256 + lane;
            #pragma unroll
            for (int q = 0; q < 4; ++q) a2[q] = fmaf(xv, wr[q * 64], a2[q]);
        }
        s1 = a2[0] + a2[1] + a2[2] + a2[3];
        s2 = fmaf(a2[0], a2[0], fmaf(a2[1], a2[1],
             fmaf(a2[2], a2[2], a2[3] * a2[3])));
        s1 = rowsum16(s1); s2 = rowsum16(s2);
        s1 += __shfl_xor(s1, 16); s2 += __shfl_xor(s2, 16);
        s1 += __shfl_xor(s1, 32); s2 += __shfl_xor(s2, 32);
        mu = s1 * (1.f / 256.f);
        rs = rsqrtf(fmaxf(s2 * (1.f / 256.f) - mu * mu, 0.f) + LN_EPS);
        #pragma unroll
        for (int q = 0; q < 4; ++q) {
            int c = q * 64 + lane;
            out[bb * 256 + c] = fmaf((a2[q] - mu) * rs, pg2[c], pbe2[c]);
        }
    }
}

// ---------------- launch ---------------------------------------------------
extern "C" void kernel_launch(void* const* d_in, const int* in_sizes, int n_in,
                              void* d_out, int out_size, void* d_ws, size_t ws_size,
                              hipStream_t stream)
{
    char* ws = (char*)d_ws;
    unsigned short* w2T    = (unsigned short*)ws;                      // 128 KB
    unsigned short* w1T    = (unsigned short*)(ws + (128u << 10));     // 96 KB
    unsigned int*   pooled = (unsigned int*)(ws + (224u << 10));       // 4 KB
    int*            done   = (int*)(ws + (228u << 10));                // 4 B

    k_prep<<<29, 256, 0, stream>>>((const float*)d_in[2], (const float*)d_in[6],
                                   w2T, w1T, pooled, done);
    k_main<<<8192, 256, 0, stream>>>((const float*)d_in[0], (const float*)d_in[1],
                                     w1T, w2T,
                                     (const float*)d_in[3], (const float*)d_in[4],
                                     (const float*)d_in[5],
                                     (const float*)d_in[7], (const float*)d_in[8],
                                     (const float*)d_in[9], pooled, done,
                                     (const float*)d_in[10], (const float*)d_in[11],
                                     (const float*)d_in[12], (const float*)d_in[13],
                                     (const float*)d_in[14], (const float*)d_in[15],
                                     (const float*)d_in[16], (const float*)d_in[17],
                                     (float*)d_out);
}